// Round 8
// baseline (76.552 us; speedup 1.0000x reference)
//
#include <hip/hip_runtime.h>
#include <hip/hip_fp16.h>

// ---- problem constants ----
#define B_     4096
#define F_     39
#define KKPAD  132
#define WPANEL ((size_t)KKPAD * 128)   // f32x4 units per Mt panel

typedef _Float16 f16x8  __attribute__((ext_vector_type(8)));
typedef float    f32x4  __attribute__((ext_vector_type(4)));
typedef float    f32x16 __attribute__((ext_vector_type(16)));

union FragAB { f16x8 h8; __half2 h2[4]; f32x4 f4; unsigned u[4]; __half h[8]; };

// ---------- W pre-pack: Wp[Mt][kk][ks][lane][j] fp16 (A-fragment order) ----------
// 32x32x16 A-frag: row o = Mt*32+(lane&31), k = 8*sub + j (sub = lane>>5)
// layer0 (kk<50):  seg=kk/10, kkin=kk%10 -> h = 4*kkin+2*ks+sub (scalar side),
//                  m = seg*8+j (vector side);  W0[o][h*39+m], pads h==39 / m==39 -> 0
// layer1 (kk>=50): seg=(kk-50)/10, kkin=(kk-50)%10 -> m = 4*kkin+2*ks+sub (scalar),
//                  h = seg*8+j (vector);        W1[o][h*39+m], pad m==39 -> 0
__global__ __launch_bounds__(256) void prep_w(
    const float* __restrict__ W0, const float* __restrict__ W1,
    __half* __restrict__ Wp)
{
    int idx = blockIdx.x * 256 + threadIdx.x;   // logical over 4*130*1024
    if (idx >= 4 * 130 * 1024) return;
    int j    = idx & 7;
    int lane = (idx >> 3) & 63;
    int ks   = (idx >> 9) & 1;
    int rest = idx >> 10;
    int kk   = rest % 130, Mt = rest / 130;
    int o    = Mt * 32 + (lane & 31);
    int sub  = lane >> 5;
    float v = 0.f;
    if (kk < 50) {
        int seg = kk / 10, kkin = kk - seg * 10;
        int h = 4 * kkin + 2 * ks + sub;
        int m = seg * 8 + j;
        if (h < 39 && m < 39) v = W0[o * 1521 + h * 39 + m];
    } else {
        int l = kk - 50;
        int seg = l / 10, kkin = l - seg * 10;
        int m = 4 * kkin + 2 * ks + sub;
        int h = seg * 8 + j;
        if (m < 39) v = W1[o * 2496 + h * 39 + m];
    }
    Wp[((size_t)(Mt * KKPAD + kk) * 2 + ks) * 512 + lane * 8 + j] = __float2half(v);
}

// ---------- compute one half-segment (5 kk = 40 MFMAs), pure registers ----------
template<int LL, int AA, int EB>
__device__ __forceinline__ void compute_half(
    const FragAB (&Areg)[5][2], const FragAB (&xmc)[4][5],
    const FragAB (&xcur)[4], f32x16 (&acc)[4], unsigned psel)
{
#pragma unroll
    for (int i = 0; i < 5; ++i) {
#pragma unroll
        for (int ks = 0; ks < 2; ++ks) {
            const int ee = EB + 2 * i + ks;   // compile-time
#pragma unroll
            for (int p = 0; p < 4; ++p) {
                unsigned bc = __builtin_amdgcn_perm(0u, xmc[p][ee >> 2].u[ee & 3], psel);
                __half2 xh2 = *(__half2*)&bc;
                FragAB bfr;
#pragma unroll
                for (int q = 0; q < 4; ++q) {
                    if constexpr (LL == 0)
                        bfr.h2[q] = __hmul2(xmc[p][AA].h2[q], xh2);
                    else
                        bfr.h2[q] = __hmul2(xcur[p].h2[q], xh2);
                }
                acc[p] = __builtin_amdgcn_mfma_f32_32x32x16_f16(
                    Areg[i][ks].h8, bfr.h8, acc[p], 0, 0, 0);
            }
        }
    }
}

// ---------- one segment (10 kk): loads clustered at half-segment boundaries ----------
template<int LL, int AA, bool LAST>
__device__ __forceinline__ void seg_body(
    const f32x4*& Apos,
    FragAB (&Aa)[5][2], FragAB (&Ab)[5][2],
    const FragAB (&xmc)[4][5], const FragAB (&xcur)[4],
    f32x16 (&acc)[4], unsigned psel)
{
    // issue loads for this segment's second half (kk +5..+9)
#pragma unroll
    for (int i = 0; i < 5; ++i) {
        Ab[i][0].f4 = Apos[(5 + i) * 128];
        Ab[i][1].f4 = Apos[(5 + i) * 128 + 64];
    }
    // compute first half from Aa (its loads issued one half-segment ago)
    compute_half<LL, AA, 0>(Aa, xmc, xcur, acc, psel);
    // issue loads for next segment's first half (kk +10..+14)
    if (!LAST) {
#pragma unroll
        for (int i = 0; i < 5; ++i) {
            Aa[i][0].f4 = Apos[(10 + i) * 128];
            Aa[i][1].f4 = Apos[(10 + i) * 128 + 64];
        }
    }
    // compute second half from Ab
    compute_half<LL, AA, 10>(Ab, xmc, xcur, acc, psel);
    Apos += 1280;
}

// ---------- main: 512 blocks x 256 thr (4 waves); wave = 32 rows (Mt=w) x 8 batches ----------
__global__ __launch_bounds__(256, 2) void cin_main(
    const float* __restrict__ x, const float* __restrict__ b0,
    const float* __restrict__ b1, const __half* __restrict__ Wp,
    float* __restrict__ out)
{
    __shared__ __align__(16) __half xT[8][16][40];    // 10 KB  [bt][d][f], f=39 zero pad
    __shared__ __align__(16) __half nhT[8][16][72];   // 18.4 KB [bt][d][h], 16B-aligned rows
    __shared__ float bs0[128], bs1[128];              // 1 KB bias

    const int t    = threadIdx.x;
    const int w    = t >> 6, lane = t & 63;           // w = Mt tile
    const int sub  = lane >> 5, bp = (lane >> 4) & 1, d = lane & 15;
    const int gb   = blockIdx.x * 8;

    // A-panel register pipeline: prologue loads kk 0..4 (cover = staging below)
    const f32x4* Apos = (const f32x4*)Wp + (size_t)w * WPANEL + lane;
    FragAB Aa[5][2], Ab[5][2];
#pragma unroll
    for (int i = 0; i < 5; ++i) {
        Aa[i][0].f4 = Apos[i * 128];
        Aa[i][1].f4 = Apos[i * 128 + 64];
    }

    if (t < 128) { bs0[t] = b0[t]; bs1[t] = b1[t]; }

    // xT fill: x[b][f][d] f32 -> xT[bt][d][f] fp16  (8 batches)
    for (int i = t; i < 1248; i += 256) {
        int bt = i / 156, r2 = i - bt * 156;
        int f = r2 >> 2, dq = r2 & 3;
        float4 v = *(const float4*)&x[((size_t)(gb + bt) * F_ + f) * 16 + dq * 4];
        xT[bt][dq * 4 + 0][f] = __float2half(v.x);
        xT[bt][dq * 4 + 1][f] = __float2half(v.y);
        xT[bt][dq * 4 + 2][f] = __float2half(v.z);
        xT[bt][dq * 4 + 3][f] = __float2half(v.w);
    }
    if (t < 128) xT[t >> 4][t & 15][39] = __float2half(0.f);
    __syncthreads();

    // register-resident x rows (per lane: its 4 batches 2p+bp), 80 VGPR
    FragAB xmc[4][5];
#pragma unroll
    for (int p = 0; p < 4; ++p)
#pragma unroll
        for (int a = 0; a < 5; ++a)
            xmc[p][a].f4 = *(const f32x4*)&xT[2 * p + bp][d][a * 8];

    // v_perm selector: broadcast lo half (sub=0) or hi half (sub=1) of a u32
    const unsigned psel = sub ? 0x03020302u : 0x01000100u;

    // acc init = b0 (C/D: col = lane&31 = bp*16+d; row = (r&3)+8*(r>>2)+4*sub)
    f32x16 acc[4];   // [pair p] -> batch 2p+bp
#pragma unroll
    for (int r = 0; r < 16; ++r) {
        float bv = bs0[w * 32 + (r & 3) + 8 * (r >> 2) + 4 * sub];
#pragma unroll
        for (int p = 0; p < 4; ++p) acc[p][r] = bv;
    }

    FragAB xcur[4];   // layer-1 vector operand (nh slice); unused in layer 0

    // ---- layer 0: 5 segments, vector operand = xmc[p][AA] (pure registers) ----
    seg_body<0, 0, false>(Apos, Aa, Ab, xmc, xcur, acc, psel);
    seg_body<0, 1, false>(Apos, Aa, Ab, xmc, xcur, acc, psel);
    seg_body<0, 2, false>(Apos, Aa, Ab, xmc, xcur, acc, psel);
    seg_body<0, 3, false>(Apos, Aa, Ab, xmc, xcur, acc, psel);
    seg_body<0, 4, false>(Apos, Aa, Ab, xmc, xcur, acc, psel);

    // ---- layer0 -> layer1 transition (A-prefetch for layer1 seg0 already in flight) ----
    if (w < 2) {
        // rows 0..63 -> nhT (fp16)
#pragma unroll
        for (int p = 0; p < 4; ++p) {
            __half* nr = &nhT[2 * p + bp][d][0];
#pragma unroll
            for (int rq = 0; rq < 4; ++rq) {
                union { __half h[4]; float2 f2; } pk;
#pragma unroll
                for (int q = 0; q < 4; ++q)
                    pk.h[q] = __float2half(fmaxf(acc[p][rq * 4 + q], 0.f));
                *(float2*)(nr + w * 32 + 8 * rq + 4 * sub) = pk.f2;
            }
        }
    } else {
        // rows 64..127 -> direct0 (out cols 0..63): reduce over d
#pragma unroll
        for (int p = 0; p < 4; ++p) {
#pragma unroll
            for (int rq = 0; rq < 4; ++rq) {
                float4 s; float* sv = (float*)&s;
#pragma unroll
                for (int q = 0; q < 4; ++q) {
                    float v = fmaxf(acc[p][rq * 4 + q], 0.f);
                    v += __shfl_xor(v, 1); v += __shfl_xor(v, 2);
                    v += __shfl_xor(v, 4); v += __shfl_xor(v, 8);
                    sv[q] = v;
                }
                if (d == 0) {
                    int row = w * 32 + 8 * rq + 4 * sub;     // 64..127
                    *(float4*)&out[(size_t)(gb + 2 * p + bp) * 192 + (row - 64)] = s;
                }
            }
        }
    }
#pragma unroll
    for (int r = 0; r < 16; ++r) {
        float bv = bs1[w * 32 + (r & 3) + 8 * (r >> 2) + 4 * sub];
#pragma unroll
        for (int p = 0; p < 4; ++p) acc[p][r] = bv;
    }
    __syncthreads();   // nhT visible to all waves

    // ---- layer 1: 8 segments, vector operand = nh slice (reloaded per segment) ----
#define L1_XCUR(AA_)                                                         \
    {                                                                        \
        xcur[0].f4 = *(const f32x4*)&nhT[bp][d][(AA_) * 8];                  \
        xcur[1].f4 = *(const f32x4*)&nhT[2 + bp][d][(AA_) * 8];              \
        xcur[2].f4 = *(const f32x4*)&nhT[4 + bp][d][(AA_) * 8];              \
        xcur[3].f4 = *(const f32x4*)&nhT[6 + bp][d][(AA_) * 8];              \
    }
    L1_XCUR(0) seg_body<1, 0, false>(Apos, Aa, Ab, xmc, xcur, acc, psel);
    L1_XCUR(1) seg_body<1, 1, false>(Apos, Aa, Ab, xmc, xcur, acc, psel);
    L1_XCUR(2) seg_body<1, 2, false>(Apos, Aa, Ab, xmc, xcur, acc, psel);
    L1_XCUR(3) seg_body<1, 3, false>(Apos, Aa, Ab, xmc, xcur, acc, psel);
    L1_XCUR(4) seg_body<1, 4, false>(Apos, Aa, Ab, xmc, xcur, acc, psel);
    L1_XCUR(5) seg_body<1, 5, false>(Apos, Aa, Ab, xmc, xcur, acc, psel);
    L1_XCUR(6) seg_body<1, 6, false>(Apos, Aa, Ab, xmc, xcur, acc, psel);
    L1_XCUR(7) seg_body<1, 7, true >(Apos, Aa, Ab, xmc, xcur, acc, psel);
#undef L1_XCUR

    // ---- final epilogue: direct1 -> out cols 64..191 (all waves) ----
#pragma unroll
    for (int p = 0; p < 4; ++p) {
#pragma unroll
        for (int rq = 0; rq < 4; ++rq) {
            float4 s; float* sv = (float*)&s;
#pragma unroll
            for (int q = 0; q < 4; ++q) {
                float v = fmaxf(acc[p][rq * 4 + q], 0.f);
                v += __shfl_xor(v, 1); v += __shfl_xor(v, 2);
                v += __shfl_xor(v, 4); v += __shfl_xor(v, 8);
                sv[q] = v;
            }
            if (d == 0) {
                int row = w * 32 + 8 * rq + 4 * sub;
                *(float4*)&out[(size_t)(gb + 2 * p + bp) * 192 + 64 + row] = s;
            }
        }
    }
}

extern "C" void kernel_launch(void* const* d_in, const int* in_sizes, int n_in,
                              void* d_out, int out_size, void* d_ws, size_t ws_size,
                              hipStream_t stream) {
    const float* x  = (const float*)d_in[0];
    const float* W0 = (const float*)d_in[1];
    const float* b0 = (const float*)d_in[2];
    const float* W1 = (const float*)d_in[3];
    const float* b1 = (const float*)d_in[4];
    float* out = (float*)d_out;
    __half* Wp = (__half*)d_ws;   // 4 Mt-panels x 132 kk x 1024 halfs = 1.08 MB

    prep_w<<<(4 * 130 * 1024 + 255) / 256, 256, 0, stream>>>(W0, W1, Wp);
    cin_main<<<B_ / 8, 256, 0, stream>>>(x, b0, b1, Wp, out);
}

// Round 11
// 75.205 us; speedup vs baseline: 1.0179x; 1.0179x over previous
//
#include <hip/hip_runtime.h>
#include <hip/hip_fp16.h>
#include <stdint.h>

// ---- problem constants ----
#define B_     4096
#define F_     39
#define KKPAD  133                      // 130 real kk + 3 pad rows for tail prefetch
#define WPANEL ((size_t)KKPAD * 1024)   // halfs per Mt panel (1 kk row = 1024 halfs = 2 KB)

typedef _Float16 f16x8  __attribute__((ext_vector_type(8)));
typedef float    f32x4  __attribute__((ext_vector_type(4)));
typedef float    f32x16 __attribute__((ext_vector_type(16)));

union FragAB { f16x8 h8; __half2 h2[4]; f32x4 f4; unsigned u[4]; __half h[8]; };

__device__ __forceinline__ void gload_lds16(const void* g, void* l) {
    __builtin_amdgcn_global_load_lds(
        (const __attribute__((address_space(1))) void*)g,
        (__attribute__((address_space(3))) void*)l, 16, 0, 0);
}

// ---------- W pre-pack: Wp[Mt][kk][ks][lane][j] fp16 (A-fragment order) ----------
// 32x32x16 A-frag: row o = Mt*32+(lane&31), k = 8*sub + j (sub = lane>>5)
// layer0 (kk<50):  seg=kk/10, kkin=kk%10 -> h = 4*kkin+2*ks+sub (scalar side),
//                  m = seg*8+j (vector side);  W0[o][h*39+m], pads h==39 / m==39 -> 0
// layer1 (kk>=50): seg=(kk-50)/10, kkin=(kk-50)%10 -> m = 4*kkin+2*ks+sub (scalar),
//                  h = seg*8+j (vector);        W1[o][h*39+m], pad m==39 -> 0
__global__ __launch_bounds__(256) void prep_w(
    const float* __restrict__ W0, const float* __restrict__ W1,
    __half* __restrict__ Wp)
{
    int idx = blockIdx.x * 256 + threadIdx.x;   // logical over 4*130*1024
    if (idx >= 4 * 130 * 1024) return;
    int j    = idx & 7;
    int lane = (idx >> 3) & 63;
    int ks   = (idx >> 9) & 1;
    int rest = idx >> 10;
    int kk   = rest % 130, Mt = rest / 130;
    int o    = Mt * 32 + (lane & 31);
    int sub  = lane >> 5;
    float v = 0.f;
    if (kk < 50) {
        int seg = kk / 10, kkin = kk - seg * 10;
        int h = 4 * kkin + 2 * ks + sub;
        int m = seg * 8 + j;
        if (h < 39 && m < 39) v = W0[o * 1521 + h * 39 + m];
    } else {
        int l = kk - 50;
        int seg = l / 10, kkin = l - seg * 10;
        int m = 4 * kkin + 2 * ks + sub;
        int h = seg * 8 + j;
        if (m < 39) v = W1[o * 2496 + h * 39 + m];
    }
    Wp[(size_t)Mt * WPANEL + ((size_t)kk * 2 + ks) * 512 + lane * 8 + j] = __float2half(v);
}

// ---------- one segment = 10 kk; LDS-ring A-stream, counted vmcnt, no barriers ----
// gpf: global src of row (segment_base_kk + 3), i.e. this segment's first prefetch.
__device__ __forceinline__ void inner10(
    const __half* gpf, __half* As, int lane,
    const FragAB (&xmc)[4][5], const FragAB (&xcur)[4],
    f32x16 (&acc)[4], unsigned psel)
{
#pragma unroll
    for (int kkin = 0; kkin < 10; ++kkin) {
        const int slot = kkin % 5;            // compile-time

        // my kk's two staging ops complete; 4 (2 kk) stay in flight
        asm volatile("s_waitcnt vmcnt(4)" ::: "memory");

        FragAB A0, A1;
        A0.f4 = *(const f32x4*)(As + slot * 1024 + lane * 8);
        A1.f4 = *(const f32x4*)(As + slot * 1024 + 512 + lane * 8);

#pragma unroll
        for (int ks = 0; ks < 2; ++ks) {
            const int ee = 2 * kkin + ks;     // compile-time
#pragma unroll
            for (int p = 0; p < 4; ++p) {
                unsigned bc = __builtin_amdgcn_perm(0u, xmc[p][ee >> 2].u[ee & 3], psel);
                __half2 xh2 = *(__half2*)&bc;
                FragAB bfr;
#pragma unroll
                for (int q = 0; q < 4; ++q)
                    bfr.h2[q] = __hmul2(xcur[p].h2[q], xh2);
                acc[p] = __builtin_amdgcn_mfma_f32_32x32x16_f16(
                    (ks ? A1 : A0).h8, bfr.h8, acc[p], 0, 0, 0);
            }
        }

        // stage kk+3 into slot (kkin+3)%5 (wave-private -> no barrier needed)
        {
            const __half* g = gpf + kkin * 1024 + lane * 8;
            const int ws = ((kkin + 3) % 5) * 1024;   // compile-time
            gload_lds16(g,       As + ws);
            gload_lds16(g + 512, As + ws + 512);
        }
    }
}

// ---------- main: 512 blocks x 256 thr (4 waves); wave = 32 rows (Mt=w) x 8 batches ----------
__global__ __launch_bounds__(256, 2) void cin_main(
    const float* __restrict__ x, const float* __restrict__ b0,
    const float* __restrict__ b1, const __half* __restrict__ Wp,
    float* __restrict__ out)
{
    __shared__ __align__(16) __half Asl[4][5][1024];  // 40 KB: per-wave 5-slot ring
    __shared__ __align__(16) __half xT[8][16][40];    // 10 KB  [bt][d][f], f=39 zero pad
    __shared__ __align__(16) __half nhT[8][16][72];   // 18.4 KB [bt][d][h], 16B rows
    __shared__ float bs0[128], bs1[128];              // 1 KB bias

    const int t    = threadIdx.x;
    const int w    = t >> 6, lane = t & 63;           // w = Mt tile
    const int sub  = lane >> 5, bp = (lane >> 4) & 1, d = lane & 15;
    const int gb   = blockIdx.x * 8;

    __half* As = &Asl[w][0][0];                       // wave-uniform ring base
    const __half* gp = Wp + (size_t)w * WPANEL;       // panel base

    // prologue: stage kk 0..2 into slots 0..2 (6 gload_lds; cover = xT staging below)
#pragma unroll
    for (int k0 = 0; k0 < 3; ++k0) {
        const __half* g = gp + (size_t)k0 * 1024 + lane * 8;
        gload_lds16(g,       As + k0 * 1024);
        gload_lds16(g + 512, As + k0 * 1024 + 512);
    }

    if (t < 128) { bs0[t] = b0[t]; bs1[t] = b1[t]; }

    // xT fill: x[b][f][d] f32 -> xT[bt][d][f] fp16  (8 batches)
    for (int i = t; i < 1248; i += 256) {
        int bt = i / 156, r2 = i - bt * 156;
        int f = r2 >> 2, dq = r2 & 3;
        float4 v = *(const float4*)&x[((size_t)(gb + bt) * F_ + f) * 16 + dq * 4];
        xT[bt][dq * 4 + 0][f] = __float2half(v.x);
        xT[bt][dq * 4 + 1][f] = __float2half(v.y);
        xT[bt][dq * 4 + 2][f] = __float2half(v.z);
        xT[bt][dq * 4 + 3][f] = __float2half(v.w);
    }
    if (t < 128) xT[t >> 4][t & 15][39] = __float2half(0.f);
    __syncthreads();   // xT shared; also drains prologue staging (slots 0..2 valid)

    // register-resident x rows (per lane: its 4 batches 2p+bp), static-indexed
    FragAB xmc[4][5];
#pragma unroll
    for (int p = 0; p < 4; ++p)
#pragma unroll
        for (int a = 0; a < 5; ++a)
            xmc[p][a].f4 = *(const f32x4*)&xT[2 * p + bp][d][a * 8];

    // v_perm selector: broadcast lo half (sub=0) or hi half (sub=1) of a u32
    const unsigned psel = sub ? 0x03020302u : 0x01000100u;

    // acc init = b0 (C/D: col = lane&31 = bp*16+d; row = (r&3)+8*(r>>2)+4*sub)
    f32x16 acc[4];   // [pair p] -> batch 2p+bp
#pragma unroll
    for (int r = 0; r < 16; ++r) {
        float bv = bs0[w * 32 + (r & 3) + 8 * (r >> 2) + 4 * sub];
#pragma unroll
        for (int p = 0; p < 4; ++p) acc[p][r] = bv;
    }

    // ---- layer 0: 5 segments (rolled), vector operand = x m-slice from LDS ----
    const __half* gpf = gp + (size_t)3 * 1024;   // first in-loop prefetch row (kk=3)
#pragma unroll 1
    for (int s = 0; s < 5; ++s) {
        FragAB xcur[4];
#pragma unroll
        for (int p = 0; p < 4; ++p)
            xcur[p].f4 = *(const f32x4*)(&xT[2 * p + bp][d][0] + s * 8);
        inner10(gpf, As, lane, xmc, xcur, acc, psel);
        gpf += 10 * 1024;
    }

    // ---- layer0 -> layer1 transition ----
    if (w < 2) {
        // rows 0..63 -> nhT (fp16)
#pragma unroll
        for (int p = 0; p < 4; ++p) {
            __half* nr = &nhT[2 * p + bp][d][0];
#pragma unroll
            for (int rq = 0; rq < 4; ++rq) {
                union { __half h[4]; float2 f2; } pk;
#pragma unroll
                for (int q = 0; q < 4; ++q)
                    pk.h[q] = __float2half(fmaxf(acc[p][rq * 4 + q], 0.f));
                *(float2*)(nr + w * 32 + 8 * rq + 4 * sub) = pk.f2;
            }
        }
    } else {
        // rows 64..127 -> direct0 (out cols 0..63): reduce over d
#pragma unroll
        for (int p = 0; p < 4; ++p) {
#pragma unroll
            for (int rq = 0; rq < 4; ++rq) {
                float4 s4; float* sv = (float*)&s4;
#pragma unroll
                for (int q = 0; q < 4; ++q) {
                    float v = fmaxf(acc[p][rq * 4 + q], 0.f);
                    v += __shfl_xor(v, 1); v += __shfl_xor(v, 2);
                    v += __shfl_xor(v, 4); v += __shfl_xor(v, 8);
                    sv[q] = v;
                }
                if (d == 0) {
                    int row = w * 32 + 8 * rq + 4 * sub;     // 64..127
                    *(float4*)&out[(size_t)(gb + 2 * p + bp) * 192 + (row - 64)] = s4;
                }
            }
        }
    }
#pragma unroll
    for (int r = 0; r < 16; ++r) {
        float bv = bs1[w * 32 + (r & 3) + 8 * (r >> 2) + 4 * sub];
#pragma unroll
        for (int p = 0; p < 4; ++p) acc[p][r] = bv;
    }
    __syncthreads();   // nhT visible; drains in-flight staging (slots for kk50..52 valid)

    // ---- layer 1: 8 segments (rolled), vector operand = nh h-slice from LDS ----
#pragma unroll 1
    for (int s = 0; s < 8; ++s) {
        FragAB xcur[4];
#pragma unroll
        for (int p = 0; p < 4; ++p)
            xcur[p].f4 = *(const f32x4*)(&nhT[2 * p + bp][d][0] + s * 8);
        inner10(gpf, As, lane, xmc, xcur, acc, psel);
        gpf += 10 * 1024;
    }

    // ---- final epilogue: direct1 -> out cols 64..191 (all waves) ----
#pragma unroll
    for (int p = 0; p < 4; ++p) {
#pragma unroll
        for (int rq = 0; rq < 4; ++rq) {
            float4 s4; float* sv = (float*)&s4;
#pragma unroll
            for (int q = 0; q < 4; ++q) {
                float v = fmaxf(acc[p][rq * 4 + q], 0.f);
                v += __shfl_xor(v, 1); v += __shfl_xor(v, 2);
                v += __shfl_xor(v, 4); v += __shfl_xor(v, 8);
                sv[q] = v;
            }
            if (d == 0) {
                int row = w * 32 + 8 * rq + 4 * sub;
                *(float4*)&out[(size_t)(gb + 2 * p + bp) * 192 + 64 + row] = s4;
            }
        }
    }
}

extern "C" void kernel_launch(void* const* d_in, const int* in_sizes, int n_in,
                              void* d_out, int out_size, void* d_ws, size_t ws_size,
                              hipStream_t stream) {
    const float* x  = (const float*)d_in[0];
    const float* W0 = (const float*)d_in[1];
    const float* b0 = (const float*)d_in[2];
    const float* W1 = (const float*)d_in[3];
    const float* b1 = (const float*)d_in[4];
    float* out = (float*)d_out;
    __half* Wp = (__half*)d_ws;   // 4 Mt-panels x 133 kk x 1024 halfs = 1.09 MB

    prep_w<<<(4 * 130 * 1024 + 255) / 256, 256, 0, stream>>>(W0, W1, Wp);
    cin_main<<<B_ / 8, 256, 0, stream>>>(x, b0, b1, Wp, out);
}